// Round 1
// baseline (3072.892 us; speedup 1.0000x reference)
//
#include <hip/hip_runtime.h>
#include <math.h>

#define B_ 2
#define W_ 2048
#define C_ 1024
#define H_ 16
#define K_ 64
#define LN_EPS 1e-5f

// ---------------------------------------------------------------------------
// Block-wide sum over 256 threads (4 waves of 64)
// ---------------------------------------------------------------------------
__device__ inline float block_sum(float val) {
  __shared__ float sb[4];
  #pragma unroll
  for (int o = 32; o > 0; o >>= 1) val += __shfl_down(val, o, 64);
  int lane = threadIdx.x & 63, wid = threadIdx.x >> 6;
  if (lane == 0) sb[wid] = val;
  __syncthreads();
  float r = sb[0] + sb[1] + sb[2] + sb[3];
  __syncthreads();  // allow sb reuse on next call
  return r;
}

// ---------------------------------------------------------------------------
// LayerNorm: one block per row; handles both seq1 and seq2.
// grid = 2*B*W blocks of 256 threads; 256 * float4 = 1024 = C
// ---------------------------------------------------------------------------
__global__ __launch_bounds__(256) void ln_kernel(
    const float* __restrict__ seq1, const float* __restrict__ seq2,
    const float* __restrict__ gamma, const float* __restrict__ beta,
    float* __restrict__ x1, float* __restrict__ x2) {
  int row = blockIdx.x;
  const int nrows = B_ * W_;
  bool first = row < nrows;
  const float* src = first ? seq1 : seq2;
  float* dst = first ? x1 : x2;
  int r = first ? row : row - nrows;

  const float4* p = (const float4*)(src + (size_t)r * C_);
  float4 v = p[threadIdx.x];
  float mean = block_sum(v.x + v.y + v.z + v.w) * (1.0f / C_);
  float dx = v.x - mean, dy = v.y - mean, dz = v.z - mean, dw = v.w - mean;
  float var = block_sum(dx * dx + dy * dy + dz * dz + dw * dw) * (1.0f / C_);
  float rstd = rsqrtf(var + LN_EPS);

  float4 g = ((const float4*)gamma)[threadIdx.x];
  float4 b = ((const float4*)beta)[threadIdx.x];
  float4 o;
  o.x = dx * rstd * g.x + b.x;
  o.y = dy * rstd * g.y + b.y;
  o.z = dz * rstd * g.z + b.z;
  o.w = dw * rstd * g.w + b.w;
  ((float4*)(dst + (size_t)r * C_))[threadIdx.x] = o;
}

// ---------------------------------------------------------------------------
// QKV projection: per (w-tile, head, which) block computes a 64x64 output
// tile of  X[4096,1024] @ proj[h][1024,64]  -> [B,H,W,K].
// BM=64, BN=64(=K), BK=16; 256 threads, 4x4 outputs each.
// ---------------------------------------------------------------------------
__global__ __launch_bounds__(256) void proj_kernel(
    const float* __restrict__ x1, const float* __restrict__ x2,
    const float* __restrict__ qp, const float* __restrict__ kp,
    const float* __restrict__ vp,
    float* __restrict__ q, float* __restrict__ k, float* __restrict__ v) {
  int mt = blockIdx.x;      // 0..63 row tile
  int h = blockIdx.y;       // 0..15
  int which = blockIdx.z;   // 0=q, 1=k, 2=v
  const float* A = (which == 0) ? x1 : x2;
  const float* P = (which == 0 ? qp : (which == 1 ? kp : vp)) + (size_t)h * C_ * K_;
  float* O = (which == 0 ? q : (which == 1 ? k : v));

  __shared__ float As[16][65];  // padded: transposed scalar stores conflict-free
  __shared__ float Bs[16][64];

  int tid = threadIdx.x;
  int tx = tid & 15, ty = tid >> 4;
  float acc[4][4] = {};
  int row0 = mt * 64;

  for (int k0 = 0; k0 < C_; k0 += 16) {
    {  // A tile: 64 rows x 16 cols, transposed into As[k][m]
      int m = tid >> 2;
      int kk = (tid & 3) * 4;
      float4 av = *(const float4*)&A[(size_t)(row0 + m) * C_ + k0 + kk];
      As[kk + 0][m] = av.x; As[kk + 1][m] = av.y;
      As[kk + 2][m] = av.z; As[kk + 3][m] = av.w;
    }
    {  // B tile: 16 rows x 64 cols, direct
      int kk = tid >> 4;
      int n = (tid & 15) * 4;
      *(float4*)&Bs[kk][n] = *(const float4*)&P[(size_t)(k0 + kk) * K_ + n];
    }
    __syncthreads();
    #pragma unroll
    for (int kk = 0; kk < 16; ++kk) {
      float a[4], b[4];
      #pragma unroll
      for (int i = 0; i < 4; ++i) a[i] = As[kk][ty + 16 * i];
      #pragma unroll
      for (int j = 0; j < 4; ++j) b[j] = Bs[kk][tx + 16 * j];
      #pragma unroll
      for (int i = 0; i < 4; ++i)
        #pragma unroll
        for (int j = 0; j < 4; ++j) acc[i][j] += a[i] * b[j];
    }
    __syncthreads();
  }

  // store to [B,H,W,K]
  #pragma unroll
  for (int i = 0; i < 4; ++i) {
    int m = row0 + ty + 16 * i;   // global row in [0, B*W)
    int b = m >> 11;              // / W_
    int w = m & (W_ - 1);
    float* orow = O + (((size_t)(b * H_ + h) * W_ + w) * K_);
    #pragma unroll
    for (int j = 0; j < 4; ++j) orow[tx + 16 * j] = acc[i][j];
  }
}

// ---------------------------------------------------------------------------
// Causal flash attention. One thread = one query row (q-row + 64-wide
// accumulator in registers). K/V staged in LDS as 64-row tiles.
// grid = (W/256, H, B), block = 256. Writes directly into [B,W,C] layout.
// ---------------------------------------------------------------------------
__global__ __launch_bounds__(256) void attn_kernel(
    const float* __restrict__ q, const float* __restrict__ k,
    const float* __restrict__ v, float* __restrict__ out) {
  int b = blockIdx.z, h = blockIdx.y;
  int qi = blockIdx.x * 256 + threadIdx.x;
  const size_t bh = ((size_t)b * H_ + h) * W_ * K_;
  const float* qp = q + bh;
  const float* kp = k + bh;
  const float* vp = v + bh;

  float qreg[K_];
  #pragma unroll
  for (int c = 0; c < K_; c += 4) {
    float4 t = *(const float4*)&qp[(size_t)qi * K_ + c];
    qreg[c] = t.x; qreg[c + 1] = t.y; qreg[c + 2] = t.z; qreg[c + 3] = t.w;
  }

  float mi = -INFINITY, li = 0.0f;
  float acc[K_] = {};

  __shared__ float Ks[64 * K_];
  __shared__ float Vs[64 * K_];

  int ntiles = blockIdx.x * 4 + 4;  // covers m <= max qi in this block
  for (int t = 0; t < ntiles; ++t) {
    int m0 = t * 64;
    __syncthreads();
    #pragma unroll
    for (int j = 0; j < 4; ++j) {
      int idx4 = j * 256 + threadIdx.x;  // float4 index into 64x64 tile
      ((float4*)Ks)[idx4] = *(const float4*)&kp[(size_t)m0 * K_ + idx4 * 4];
      ((float4*)Vs)[idx4] = *(const float4*)&vp[(size_t)m0 * K_ + idx4 * 4];
    }
    __syncthreads();

    int mmax = qi - m0 + 1;           // valid keys in this tile for this row
    if (mmax > 64) mmax = 64;
    for (int m = 0; m < mmax; ++m) {
      const float* krow = &Ks[m * K_];
      float s = 0.0f;
      #pragma unroll
      for (int c = 0; c < K_; ++c) s += qreg[c] * krow[c];
      s *= 0.125f;                    // 1/sqrt(64)
      float newm = fmaxf(mi, s);
      float alpha = __expf(mi - newm);
      float p = __expf(s - newm);
      li = li * alpha + p;
      const float* vrow = &Vs[m * K_];
      #pragma unroll
      for (int c = 0; c < K_; ++c) acc[c] = acc[c] * alpha + p * vrow[c];
      mi = newm;
    }
  }

  float inv = 1.0f / li;
  float* orow = out + ((size_t)(b * W_ + qi) * C_) + h * K_;
  #pragma unroll
  for (int c = 0; c < K_; c += 4) {
    float4 o;
    o.x = acc[c] * inv; o.y = acc[c + 1] * inv;
    o.z = acc[c + 2] * inv; o.w = acc[c + 3] * inv;
    *(float4*)&orow[c] = o;
  }
}

// ---------------------------------------------------------------------------
// Mixer: out[m][n] = sum_j attn[m][j] * Wm[n][j] + bias[n]
// (Wm accessed transposed). BM=64, BN=64, BK=16; grid (64, 16).
// ---------------------------------------------------------------------------
__global__ __launch_bounds__(256) void mixer_kernel(
    const float* __restrict__ A, const float* __restrict__ Wm,
    const float* __restrict__ bias, float* __restrict__ out) {
  int mt = blockIdx.x, nt = blockIdx.y;
  __shared__ float As[16][65];
  __shared__ float Bs[16][65];
  int tid = threadIdx.x;
  int tx = tid & 15, ty = tid >> 4;
  float acc[4][4] = {};
  int row0 = mt * 64, col0 = nt * 64;

  for (int k0 = 0; k0 < C_; k0 += 16) {
    {
      int m = tid >> 2;
      int kk = (tid & 3) * 4;
      float4 av = *(const float4*)&A[(size_t)(row0 + m) * C_ + k0 + kk];
      As[kk + 0][m] = av.x; As[kk + 1][m] = av.y;
      As[kk + 2][m] = av.z; As[kk + 3][m] = av.w;
    }
    {
      int n = tid >> 2;
      int kk = (tid & 3) * 4;
      float4 bv = *(const float4*)&Wm[(size_t)(col0 + n) * C_ + k0 + kk];
      Bs[kk + 0][n] = bv.x; Bs[kk + 1][n] = bv.y;
      Bs[kk + 2][n] = bv.z; Bs[kk + 3][n] = bv.w;
    }
    __syncthreads();
    #pragma unroll
    for (int kk = 0; kk < 16; ++kk) {
      float a[4], b[4];
      #pragma unroll
      for (int i = 0; i < 4; ++i) a[i] = As[kk][ty + 16 * i];
      #pragma unroll
      for (int j = 0; j < 4; ++j) b[j] = Bs[kk][tx + 16 * j];
      #pragma unroll
      for (int i = 0; i < 4; ++i)
        #pragma unroll
        for (int j = 0; j < 4; ++j) acc[i][j] += a[i] * b[j];
    }
    __syncthreads();
  }

  #pragma unroll
  for (int i = 0; i < 4; ++i) {
    int m = row0 + ty + 16 * i;
    #pragma unroll
    for (int j = 0; j < 4; ++j) {
      int n = col0 + tx + 16 * j;
      out[(size_t)m * C_ + n] = acc[i][j] + bias[n];
    }
  }
}

// ---------------------------------------------------------------------------
extern "C" void kernel_launch(void* const* d_in, const int* in_sizes, int n_in,
                              void* d_out, int out_size, void* d_ws, size_t ws_size,
                              hipStream_t stream) {
  const float* seq1  = (const float*)d_in[0];
  const float* seq2  = (const float*)d_in[1];
  const float* gamma = (const float*)d_in[2];
  const float* beta  = (const float*)d_in[3];
  const float* qp    = (const float*)d_in[4];
  const float* kp    = (const float*)d_in[5];
  const float* vp    = (const float*)d_in[6];
  const float* wm    = (const float*)d_in[7];
  const float* mb    = (const float*)d_in[8];
  float* out = (float*)d_out;

  char* ws = (char*)d_ws;
  const size_t NROW = (size_t)B_ * W_;        // 4096
  const size_t XSZ = NROW * C_ * sizeof(float);  // 16 MB per [B,W,C]/[B,H,W,K] buffer
  float* x1 = (float*)(ws);            // later reused as attention output [B,W,C]
  float* x2 = (float*)(ws + XSZ);
  float* q  = (float*)(ws + 2 * XSZ);
  float* kk = (float*)(ws + 3 * XSZ);
  float* vv = (float*)(ws + 4 * XSZ);
  float* attn = x1;

  ln_kernel<<<dim3(2 * (unsigned)NROW), dim3(256), 0, stream>>>(
      seq1, seq2, gamma, beta, x1, x2);
  proj_kernel<<<dim3(64, H_, 3), dim3(256), 0, stream>>>(
      x1, x2, qp, kp, vp, q, kk, vv);
  attn_kernel<<<dim3(W_ / 256, H_, B_), dim3(256), 0, stream>>>(q, kk, vv, attn);
  mixer_kernel<<<dim3(64, 16), dim3(256), 0, stream>>>(attn, wm, mb, out);
}

// Round 2
// 1339.054 us; speedup vs baseline: 2.2948x; 2.2948x over previous
//
#include <hip/hip_runtime.h>
#include <math.h>

#define B_ 2
#define W_ 2048
#define C_ 1024
#define H_ 16
#define K_ 64
#define LN_EPS 1e-5f
#define SEG_ 4
#define SEGK (W_ / SEG_)   // 512 keys per segment

// ---------------------------------------------------------------------------
// Block-wide sum over 256 threads (4 waves of 64)
// ---------------------------------------------------------------------------
__device__ inline float block_sum(float val) {
  __shared__ float sb[4];
  #pragma unroll
  for (int o = 32; o > 0; o >>= 1) val += __shfl_down(val, o, 64);
  int lane = threadIdx.x & 63, wid = threadIdx.x >> 6;
  if (lane == 0) sb[wid] = val;
  __syncthreads();
  float r = sb[0] + sb[1] + sb[2] + sb[3];
  __syncthreads();
  return r;
}

// ---------------------------------------------------------------------------
// LayerNorm: one block per row; handles both seq1 and seq2.
// ---------------------------------------------------------------------------
__global__ __launch_bounds__(256) void ln_kernel(
    const float* __restrict__ seq1, const float* __restrict__ seq2,
    const float* __restrict__ gamma, const float* __restrict__ beta,
    float* __restrict__ x1, float* __restrict__ x2) {
  int row = blockIdx.x;
  const int nrows = B_ * W_;
  bool first = row < nrows;
  const float* src = first ? seq1 : seq2;
  float* dst = first ? x1 : x2;
  int r = first ? row : row - nrows;

  const float4* p = (const float4*)(src + (size_t)r * C_);
  float4 v = p[threadIdx.x];
  float mean = block_sum(v.x + v.y + v.z + v.w) * (1.0f / C_);
  float dx = v.x - mean, dy = v.y - mean, dz = v.z - mean, dw = v.w - mean;
  float var = block_sum(dx * dx + dy * dy + dz * dz + dw * dw) * (1.0f / C_);
  float rstd = rsqrtf(var + LN_EPS);

  float4 g = ((const float4*)gamma)[threadIdx.x];
  float4 b = ((const float4*)beta)[threadIdx.x];
  float4 o;
  o.x = dx * rstd * g.x + b.x;
  o.y = dy * rstd * g.y + b.y;
  o.z = dz * rstd * g.z + b.z;
  o.w = dw * rstd * g.w + b.w;
  ((float4*)(dst + (size_t)r * C_))[threadIdx.x] = o;
}

// ---------------------------------------------------------------------------
// QKV projection (unchanged from R1): 64x64 tile of X[4096,1024]@proj[h]
// ---------------------------------------------------------------------------
__global__ __launch_bounds__(256) void proj_kernel(
    const float* __restrict__ x1, const float* __restrict__ x2,
    const float* __restrict__ qp, const float* __restrict__ kp,
    const float* __restrict__ vp,
    float* __restrict__ q, float* __restrict__ k, float* __restrict__ v) {
  int mt = blockIdx.x;
  int h = blockIdx.y;
  int which = blockIdx.z;
  const float* A = (which == 0) ? x1 : x2;
  const float* P = (which == 0 ? qp : (which == 1 ? kp : vp)) + (size_t)h * C_ * K_;
  float* O = (which == 0 ? q : (which == 1 ? k : v));

  __shared__ float As[16][65];
  __shared__ float Bs[16][64];

  int tid = threadIdx.x;
  int tx = tid & 15, ty = tid >> 4;
  float acc[4][4] = {};
  int row0 = mt * 64;

  for (int k0 = 0; k0 < C_; k0 += 16) {
    {
      int m = tid >> 2;
      int kk = (tid & 3) * 4;
      float4 av = *(const float4*)&A[(size_t)(row0 + m) * C_ + k0 + kk];
      As[kk + 0][m] = av.x; As[kk + 1][m] = av.y;
      As[kk + 2][m] = av.z; As[kk + 3][m] = av.w;
    }
    {
      int kk = tid >> 4;
      int n = (tid & 15) * 4;
      *(float4*)&Bs[kk][n] = *(const float4*)&P[(size_t)(k0 + kk) * K_ + n];
    }
    __syncthreads();
    #pragma unroll
    for (int kk = 0; kk < 16; ++kk) {
      float a[4], b[4];
      #pragma unroll
      for (int i = 0; i < 4; ++i) a[i] = As[kk][ty + 16 * i];
      #pragma unroll
      for (int j = 0; j < 4; ++j) b[j] = Bs[kk][tx + 16 * j];
      #pragma unroll
      for (int i = 0; i < 4; ++i)
        #pragma unroll
        for (int j = 0; j < 4; ++j) acc[i][j] += a[i] * b[j];
    }
    __syncthreads();
  }

  #pragma unroll
  for (int i = 0; i < 4; ++i) {
    int m = row0 + ty + 16 * i;
    int b = m >> 11;
    int w = m & (W_ - 1);
    float* orow = O + (((size_t)(b * H_ + h) * W_ + w) * K_);
    #pragma unroll
    for (int j = 0; j < 4; ++j) orow[tx + 16 * j] = acc[i][j];
  }
}

// ---------------------------------------------------------------------------
// Causal flash attention, key-split (flash-decoding) partial pass.
// grid = (W/256, B*H, SEG_), block = 256; one thread = one query row for a
// 512-key segment. Chunk-batched online softmax (8 keys/chunk) for ILP.
// Writes unnormalized partials (m, l, acc[64]) to workspace.
// ---------------------------------------------------------------------------
__global__ __launch_bounds__(256, 2) void attn_partial_kernel(
    const float* __restrict__ q, const float* __restrict__ k,
    const float* __restrict__ v,
    float* __restrict__ pm, float* __restrict__ pl, float* __restrict__ pacc) {
  int bh = blockIdx.y;
  int seg = blockIdx.z;
  int qi = blockIdx.x * 256 + threadIdx.x;
  const size_t base = (size_t)bh * W_ * K_;
  const float* qp = q + base;
  const float* kp = k + base;
  const float* vp = v + base;

  float qreg[K_];
  #pragma unroll
  for (int c = 0; c < K_; c += 4) {
    float4 t = *(const float4*)&qp[(size_t)qi * K_ + c];
    qreg[c] = t.x; qreg[c + 1] = t.y; qreg[c + 2] = t.z; qreg[c + 3] = t.w;
  }

  float mi = -INFINITY, li = 0.0f;
  float acc[K_] = {};

  __shared__ float Ks[64 * K_];
  __shared__ float Vs[64 * K_];

  int lo = seg * SEGK;
  int hi = lo + SEGK;
  int qend = blockIdx.x * 256 + 256;
  if (hi > qend) hi = qend;          // no key tile beyond this block's max query

  for (int m0 = lo; m0 < hi; m0 += 64) {
    __syncthreads();
    #pragma unroll
    for (int j = 0; j < 4; ++j) {
      int idx4 = j * 256 + threadIdx.x;
      ((float4*)Ks)[idx4] = *(const float4*)&kp[(size_t)m0 * K_ + idx4 * 4];
      ((float4*)Vs)[idx4] = *(const float4*)&vp[(size_t)m0 * K_ + idx4 * 4];
    }
    __syncthreads();

    if (qi >= m0) {
      int nvalid = qi - m0 + 1;      // >= 1; may exceed 64 (full tile)
      for (int c8 = 0; c8 < 8; ++c8) {
        int mb = c8 * 8;
        if (mb >= nvalid) break;
        // ---- scores for 8 keys (independent 4-wide partial chains) ----
        float s8[8];
        #pragma unroll
        for (int j = 0; j < 8; ++j) {
          const float* kr = &Ks[(mb + j) * K_];
          float ax = 0.f, ay = 0.f, az = 0.f, aw = 0.f;
          #pragma unroll
          for (int c4 = 0; c4 < 16; ++c4) {
            float4 kv = *(const float4*)&kr[c4 * 4];   // wave-uniform: broadcast
            ax = fmaf(qreg[4 * c4 + 0], kv.x, ax);
            ay = fmaf(qreg[4 * c4 + 1], kv.y, ay);
            az = fmaf(qreg[4 * c4 + 2], kv.z, az);
            aw = fmaf(qreg[4 * c4 + 3], kv.w, aw);
          }
          s8[j] = ((ax + ay) + (az + aw)) * 0.125f;
        }
        // ---- online softmax update, once per 8-key chunk ----
        float tmax = -INFINITY;
        #pragma unroll
        for (int j = 0; j < 8; ++j)
          tmax = fmaxf(tmax, (mb + j < nvalid) ? s8[j] : -INFINITY);
        float newm = fmaxf(mi, tmax);
        float alpha = __expf(fminf(mi - newm, 0.0f));   // NaN-safe when both -inf
        float psum = 0.f;
        #pragma unroll
        for (int j = 0; j < 8; ++j) {
          float p = (mb + j < nvalid) ? __expf(s8[j] - newm) : 0.0f;
          s8[j] = p;
          psum += p;
        }
        li = li * alpha + psum;
        #pragma unroll
        for (int c = 0; c < K_; ++c) acc[c] *= alpha;
        #pragma unroll
        for (int j = 0; j < 8; ++j) {
          float p = s8[j];
          const float* vr = &Vs[(mb + j) * K_];
          #pragma unroll
          for (int c4 = 0; c4 < 16; ++c4) {
            float4 vv = *(const float4*)&vr[c4 * 4];   // wave-uniform: broadcast
            acc[4 * c4 + 0] = fmaf(p, vv.x, acc[4 * c4 + 0]);
            acc[4 * c4 + 1] = fmaf(p, vv.y, acc[4 * c4 + 1]);
            acc[4 * c4 + 2] = fmaf(p, vv.z, acc[4 * c4 + 2]);
            acc[4 * c4 + 3] = fmaf(p, vv.w, acc[4 * c4 + 3]);
          }
        }
        mi = newm;
      }
    }
  }

  // ---- write partials (always, including empty segments) ----
  size_t pidx = ((size_t)bh * SEG_ + seg) * W_ + qi;
  pm[pidx] = mi;
  pl[pidx] = li;
  float* pa = pacc + pidx * K_;
  #pragma unroll
  for (int c = 0; c < K_; c += 4) {
    float4 t;
    t.x = acc[c]; t.y = acc[c + 1]; t.z = acc[c + 2]; t.w = acc[c + 3];
    *(float4*)&pa[c] = t;
  }
}

// ---------------------------------------------------------------------------
// Combine key-split partials: out = sum_s exp(m_s-M)*acc_s / sum_s l_s*exp(m_s-M)
// One thread per (bh, q, c). Writes directly into [B,W,C] layout.
// ---------------------------------------------------------------------------
__global__ __launch_bounds__(256) void attn_combine_kernel(
    const float* __restrict__ pm, const float* __restrict__ pl,
    const float* __restrict__ pacc, float* __restrict__ out) {
  int gid = blockIdx.x * 256 + threadIdx.x;
  int c = gid & 63;
  int qq = (gid >> 6) & (W_ - 1);
  int bh = gid >> 17;
  size_t base = (size_t)bh * SEG_ * W_ + qq;

  float ms[SEG_], ls[SEG_];
  float M = -INFINITY;
  #pragma unroll
  for (int s = 0; s < SEG_; ++s) {
    ms[s] = pm[base + (size_t)s * W_];
    ls[s] = pl[base + (size_t)s * W_];
    M = fmaxf(M, ms[s]);
  }
  float L = 0.f, o = 0.f;
  #pragma unroll
  for (int s = 0; s < SEG_; ++s) {
    float sc = __expf(ms[s] - M);   // M finite always (seg 0 non-empty)
    L += ls[s] * sc;
    o += sc * pacc[(base + (size_t)s * W_) * K_ + c];
  }
  int b = bh >> 4, h = bh & 15;
  out[((size_t)(b * W_ + qq)) * C_ + h * K_ + c] = o / L;
}

// ---------------------------------------------------------------------------
// Mixer (unchanged from R1)
// ---------------------------------------------------------------------------
__global__ __launch_bounds__(256) void mixer_kernel(
    const float* __restrict__ A, const float* __restrict__ Wm,
    const float* __restrict__ bias, float* __restrict__ out) {
  int mt = blockIdx.x, nt = blockIdx.y;
  __shared__ float As[16][65];
  __shared__ float Bs[16][65];
  int tid = threadIdx.x;
  int tx = tid & 15, ty = tid >> 4;
  float acc[4][4] = {};
  int row0 = mt * 64, col0 = nt * 64;

  for (int k0 = 0; k0 < C_; k0 += 16) {
    {
      int m = tid >> 2;
      int kk = (tid & 3) * 4;
      float4 av = *(const float4*)&A[(size_t)(row0 + m) * C_ + k0 + kk];
      As[kk + 0][m] = av.x; As[kk + 1][m] = av.y;
      As[kk + 2][m] = av.z; As[kk + 3][m] = av.w;
    }
    {
      int n = tid >> 2;
      int kk = (tid & 3) * 4;
      float4 bv = *(const float4*)&Wm[(size_t)(col0 + n) * C_ + k0 + kk];
      Bs[kk + 0][n] = bv.x; Bs[kk + 1][n] = bv.y;
      Bs[kk + 2][n] = bv.z; Bs[kk + 3][n] = bv.w;
    }
    __syncthreads();
    #pragma unroll
    for (int kk = 0; kk < 16; ++kk) {
      float a[4], b[4];
      #pragma unroll
      for (int i = 0; i < 4; ++i) a[i] = As[kk][ty + 16 * i];
      #pragma unroll
      for (int j = 0; j < 4; ++j) b[j] = Bs[kk][tx + 16 * j];
      #pragma unroll
      for (int i = 0; i < 4; ++i)
        #pragma unroll
        for (int j = 0; j < 4; ++j) acc[i][j] += a[i] * b[j];
    }
    __syncthreads();
  }

  #pragma unroll
  for (int i = 0; i < 4; ++i) {
    int m = row0 + ty + 16 * i;
    #pragma unroll
    for (int j = 0; j < 4; ++j) {
      int n = col0 + tx + 16 * j;
      out[(size_t)m * C_ + n] = acc[i][j] + bias[n];
    }
  }
}

// ---------------------------------------------------------------------------
extern "C" void kernel_launch(void* const* d_in, const int* in_sizes, int n_in,
                              void* d_out, int out_size, void* d_ws, size_t ws_size,
                              hipStream_t stream) {
  const float* seq1  = (const float*)d_in[0];
  const float* seq2  = (const float*)d_in[1];
  const float* gamma = (const float*)d_in[2];
  const float* beta  = (const float*)d_in[3];
  const float* qp    = (const float*)d_in[4];
  const float* kp    = (const float*)d_in[5];
  const float* vp    = (const float*)d_in[6];
  const float* wm    = (const float*)d_in[7];
  const float* mb    = (const float*)d_in[8];
  float* out = (float*)d_out;

  char* ws = (char*)d_ws;
  const size_t NROW = (size_t)B_ * W_;              // 4096
  const size_t XSZ = NROW * C_ * sizeof(float);     // 16 MB
  const size_t NPQ = (size_t)B_ * H_ * SEG_ * W_;   // 262144 partial slots
  float* x1 = (float*)(ws);                          // later: attention output
  float* x2 = (float*)(ws + XSZ);
  float* q  = (float*)(ws + 2 * XSZ);
  float* kk = (float*)(ws + 3 * XSZ);
  float* vv = (float*)(ws + 4 * XSZ);
  float* pm = (float*)(ws + 5 * XSZ);
  float* pl = (float*)(ws + 5 * XSZ + NPQ * sizeof(float));
  float* pacc = (float*)(ws + 5 * XSZ + 2 * NPQ * sizeof(float));
  float* attn = x1;

  ln_kernel<<<dim3(2 * (unsigned)NROW), dim3(256), 0, stream>>>(
      seq1, seq2, gamma, beta, x1, x2);
  proj_kernel<<<dim3(64, H_, 3), dim3(256), 0, stream>>>(
      x1, x2, qp, kp, vp, q, kk, vv);
  attn_partial_kernel<<<dim3(W_ / 256, B_ * H_, SEG_), dim3(256), 0, stream>>>(
      q, kk, vv, pm, pl, pacc);
  attn_combine_kernel<<<dim3((unsigned)(NROW * H_ * K_ / 256)), dim3(256), 0, stream>>>(
      pm, pl, pacc, attn);
  mixer_kernel<<<dim3(64, 16), dim3(256), 0, stream>>>(attn, wm, mb, out);
}

// Round 3
// 873.648 us; speedup vs baseline: 3.5173x; 1.5327x over previous
//
#include <hip/hip_runtime.h>
#include <math.h>

#define B_ 2
#define W_ 2048
#define C_ 1024
#define H_ 16
#define K_ 64
#define LN_EPS 1e-5f

typedef __attribute__((ext_vector_type(8))) short short8;   // 8 bf16 (4 VGPRs)
typedef __attribute__((ext_vector_type(4))) float float4v;  // MFMA C/D frag

__device__ inline unsigned short f2bf(float f) {  // RNE float->bf16
  unsigned u = __float_as_uint(f);
  u += 0x7fffu + ((u >> 16) & 1u);
  return (unsigned short)(u >> 16);
}

// ---------------------------------------------------------------------------
// Block-wide sum over 256 threads (4 waves of 64)
// ---------------------------------------------------------------------------
__device__ inline float block_sum(float val) {
  __shared__ float sb[4];
  #pragma unroll
  for (int o = 32; o > 0; o >>= 1) val += __shfl_down(val, o, 64);
  int lane = threadIdx.x & 63, wid = threadIdx.x >> 6;
  if (lane == 0) sb[wid] = val;
  __syncthreads();
  float r = sb[0] + sb[1] + sb[2] + sb[3];
  __syncthreads();
  return r;
}

// ---------------------------------------------------------------------------
// LayerNorm (unchanged): one block per row; handles both seq1 and seq2.
// ---------------------------------------------------------------------------
__global__ __launch_bounds__(256) void ln_kernel(
    const float* __restrict__ seq1, const float* __restrict__ seq2,
    const float* __restrict__ gamma, const float* __restrict__ beta,
    float* __restrict__ x1, float* __restrict__ x2) {
  int row = blockIdx.x;
  const int nrows = B_ * W_;
  bool first = row < nrows;
  const float* src = first ? seq1 : seq2;
  float* dst = first ? x1 : x2;
  int r = first ? row : row - nrows;

  const float4* p = (const float4*)(src + (size_t)r * C_);
  float4 v = p[threadIdx.x];
  float mean = block_sum(v.x + v.y + v.z + v.w) * (1.0f / C_);
  float dx = v.x - mean, dy = v.y - mean, dz = v.z - mean, dw = v.w - mean;
  float var = block_sum(dx * dx + dy * dy + dz * dz + dw * dw) * (1.0f / C_);
  float rstd = rsqrtf(var + LN_EPS);

  float4 g = ((const float4*)gamma)[threadIdx.x];
  float4 b = ((const float4*)beta)[threadIdx.x];
  float4 o;
  o.x = dx * rstd * g.x + b.x;
  o.y = dy * rstd * g.y + b.y;
  o.z = dz * rstd * g.z + b.z;
  o.w = dw * rstd * g.w + b.w;
  ((float4*)(dst + (size_t)r * C_))[threadIdx.x] = o;
}

// ---------------------------------------------------------------------------
// QKV projection (fp32 compute; NEW: bf16 outputs).
// q: [B,H,W,K] bf16, pre-scaled by 1/sqrt(K).  k: [B,H,W,K] bf16.
// v: TRANSPOSED [B,H,K,W] bf16 (so attention V B-frags are contiguous).
// Thread now owns cols tx*4..tx*4+3 (contiguous -> packed 8B stores).
// ---------------------------------------------------------------------------
__global__ __launch_bounds__(256) void proj_kernel(
    const float* __restrict__ x1, const float* __restrict__ x2,
    const float* __restrict__ qp, const float* __restrict__ kp,
    const float* __restrict__ vp,
    short* __restrict__ q, short* __restrict__ k, short* __restrict__ vt) {
  int mt = blockIdx.x;
  int h = blockIdx.y;
  int which = blockIdx.z;
  const float* A = (which == 0) ? x1 : x2;
  const float* P = (which == 0 ? qp : (which == 1 ? kp : vp)) + (size_t)h * C_ * K_;

  __shared__ float As[16][65];
  __shared__ float Bs[16][64];

  int tid = threadIdx.x;
  int tx = tid & 15, ty = tid >> 4;
  float acc[4][4] = {};
  int row0 = mt * 64;

  for (int k0 = 0; k0 < C_; k0 += 16) {
    {
      int m = tid >> 2;
      int kk = (tid & 3) * 4;
      float4 av = *(const float4*)&A[(size_t)(row0 + m) * C_ + k0 + kk];
      As[kk + 0][m] = av.x; As[kk + 1][m] = av.y;
      As[kk + 2][m] = av.z; As[kk + 3][m] = av.w;
    }
    {
      int kk = tid >> 4;
      int n = (tid & 15) * 4;
      *(float4*)&Bs[kk][n] = *(const float4*)&P[(size_t)(k0 + kk) * K_ + n];
    }
    __syncthreads();
    #pragma unroll
    for (int kk = 0; kk < 16; ++kk) {
      float a[4], b[4];
      #pragma unroll
      for (int i = 0; i < 4; ++i) a[i] = As[kk][ty + 16 * i];
      #pragma unroll
      for (int j = 0; j < 4; ++j) b[j] = Bs[kk][tx * 4 + j];
      #pragma unroll
      for (int i = 0; i < 4; ++i)
        #pragma unroll
        for (int j = 0; j < 4; ++j) acc[i][j] += a[i] * b[j];
    }
    __syncthreads();
  }

  if (which <= 1) {  // q (scaled) or k, row-major [B,H,W,K] bf16
    float scale = (which == 0) ? 0.125f : 1.0f;
    short* O = (which == 0) ? q : k;
    #pragma unroll
    for (int i = 0; i < 4; ++i) {
      int m = row0 + ty + 16 * i;
      int b = m >> 11;
      int w = m & (W_ - 1);
      short* orow = O + ((size_t)(b * H_ + h) * W_ + w) * K_;
      unsigned short h0 = f2bf(acc[i][0] * scale), h1 = f2bf(acc[i][1] * scale);
      unsigned short h2 = f2bf(acc[i][2] * scale), h3 = f2bf(acc[i][3] * scale);
      uint2 pk;
      pk.x = (unsigned)h0 | ((unsigned)h1 << 16);
      pk.y = (unsigned)h2 | ((unsigned)h3 << 16);
      *(uint2*)(orow + tx * 4) = pk;
    }
  } else {  // v transposed [B,H,K,W] bf16
    #pragma unroll
    for (int i = 0; i < 4; ++i) {
      int m = row0 + ty + 16 * i;
      int b = m >> 11;
      int w = m & (W_ - 1);
      #pragma unroll
      for (int j = 0; j < 4; ++j)
        vt[((size_t)(b * H_ + h) * K_ + tx * 4 + j) * W_ + w] =
            (short)f2bf(acc[i][j]);
    }
  }
}

// ---------------------------------------------------------------------------
// Causal flash attention, bf16 MFMA. grid=(32, B*H), block=256 (4 waves).
// Block handles 64 q-rows (wave w -> 16 rows). Per key-tile of 64:
//   S = Q·K^T (8x mfma 16x16x32), online softmax in C-layout,
//   P -> bf16 via wave-private LDS (C-layout -> A-layout), O += P·V (8x mfma).
// K read as B^T frags straight from global; V read from pre-transposed vt.
// Q pre-scaled by 1/sqrt(K) in proj. Output fp32 [B,W,C].
// ---------------------------------------------------------------------------
__global__ __launch_bounds__(256) void attn_mfma_kernel(
    const short* __restrict__ q, const short* __restrict__ k,
    const short* __restrict__ vt, float* __restrict__ out) {
  int bh = blockIdx.y;
  int b = bh >> 4, h = bh & 15;
  int qt = (int)gridDim.x - 1 - (int)blockIdx.x;  // heavy tiles first
  int wave = threadIdx.x >> 6;
  int lane = threadIdx.x & 63;
  int lg = lane >> 4;   // quad 0..3
  int ll = lane & 15;

  const short* qp = q + (size_t)bh * W_ * K_;
  const short* kp = k + (size_t)bh * W_ * K_;
  const short* vb = vt + (size_t)bh * K_ * W_;

  // Q A-frags: lane holds Q[m=ll][kc*32 + lg*8 + j], rows wave*16+ll
  int qrow = qt * 64 + wave * 16 + ll;
  short8 aq[2];
  #pragma unroll
  for (int kc = 0; kc < 2; ++kc)
    aq[kc] = *(const short8*)(qp + (size_t)qrow * K_ + kc * 32 + lg * 8);

  float4v o[4];
  #pragma unroll
  for (int nt = 0; nt < 4; ++nt) { o[nt][0] = 0.f; o[nt][1] = 0.f; o[nt][2] = 0.f; o[nt][3] = 0.f; }
  float m4[4] = {-INFINITY, -INFINITY, -INFINITY, -INFINITY};
  float l4[4] = {};

  __shared__ short Plds[4 * 16 * 72];  // per-wave 16 rows x stride 72 bf16
  short* myP = &Plds[wave * 16 * 72];

  for (int kt = 0; kt <= qt; ++kt) {
    const short* kbase = kp + (size_t)kt * 64 * K_;
    // ---- S = Q·K^T ----
    float4v S[4];
    #pragma unroll
    for (int nt = 0; nt < 4; ++nt) {
      S[nt][0] = 0.f; S[nt][1] = 0.f; S[nt][2] = 0.f; S[nt][3] = 0.f;
      #pragma unroll
      for (int kc = 0; kc < 2; ++kc) {
        short8 bk = *(const short8*)(kbase + (size_t)(nt * 16 + ll) * K_ + kc * 32 + lg * 8);
        S[nt] = __builtin_amdgcn_mfma_f32_16x16x32_bf16(aq[kc], bk, S[nt], 0, 0, 0);
      }
    }
    // ---- causal mask (diagonal tile only) ----
    float sv[4][4];
    #pragma unroll
    for (int nt = 0; nt < 4; ++nt)
      #pragma unroll
      for (int r = 0; r < 4; ++r) sv[nt][r] = S[nt][r];
    if (kt == qt) {
      #pragma unroll
      for (int nt = 0; nt < 4; ++nt) {
        #pragma unroll
        for (int r = 0; r < 4; ++r) {
          int col = nt * 16 + ll;               // key within tile
          int row = wave * 16 + lg * 4 + r;     // query within tile
          if (col > row) sv[nt][r] = -INFINITY;
        }
      }
    }
    // ---- online softmax (row stats via 16-lane butterflies) ----
    float pv[4][4];
    #pragma unroll
    for (int r = 0; r < 4; ++r) {
      float x = fmaxf(fmaxf(sv[0][r], sv[1][r]), fmaxf(sv[2][r], sv[3][r]));
      x = fmaxf(x, __shfl_xor(x, 1, 64));
      x = fmaxf(x, __shfl_xor(x, 2, 64));
      x = fmaxf(x, __shfl_xor(x, 4, 64));
      x = fmaxf(x, __shfl_xor(x, 8, 64));
      float nm = fmaxf(m4[r], x);               // finite: col<=row exists
      float al = __expf(m4[r] - nm);            // first iter: exp(-inf)=0
      m4[r] = nm;
      float ps = 0.f;
      #pragma unroll
      for (int nt = 0; nt < 4; ++nt) {
        float p = __expf(sv[nt][r] - nm);
        pv[nt][r] = p;
        ps += p;
      }
      ps += __shfl_xor(ps, 1, 64);
      ps += __shfl_xor(ps, 2, 64);
      ps += __shfl_xor(ps, 4, 64);
      ps += __shfl_xor(ps, 8, 64);
      l4[r] = l4[r] * al + ps;
      #pragma unroll
      for (int nt = 0; nt < 4; ++nt) o[nt][r] *= al;
    }
    // ---- P (C-layout) -> bf16 -> LDS -> A-layout. Wave-private: no barrier.
    #pragma unroll
    for (int nt = 0; nt < 4; ++nt)
      #pragma unroll
      for (int r = 0; r < 4; ++r)
        myP[(lg * 4 + r) * 72 + nt * 16 + ll] = (short)f2bf(pv[nt][r]);
    __builtin_amdgcn_s_waitcnt(0xC07F);  // lgkmcnt(0): DS writes visible to reads
    short8 ap[2];
    ap[0] = *(const short8*)(myP + ll * 72 + lg * 8);
    ap[1] = *(const short8*)(myP + ll * 72 + 32 + lg * 8);
    // ---- O += P·V ----
    #pragma unroll
    for (int nt = 0; nt < 4; ++nt) {
      #pragma unroll
      for (int kc = 0; kc < 2; ++kc) {
        short8 bv = *(const short8*)(vb + (size_t)(nt * 16 + ll) * W_ + kt * 64 + kc * 32 + lg * 8);
        o[nt] = __builtin_amdgcn_mfma_f32_16x16x32_bf16(ap[kc], bv, o[nt], 0, 0, 0);
      }
    }
  }

  // ---- epilogue: normalize, write fp32 [B,W,C] ----
  float inv[4];
  #pragma unroll
  for (int r = 0; r < 4; ++r) inv[r] = 1.0f / l4[r];
  #pragma unroll
  for (int nt = 0; nt < 4; ++nt) {
    #pragma unroll
    for (int r = 0; r < 4; ++r) {
      int row = qt * 64 + wave * 16 + lg * 4 + r;
      out[((size_t)(b * W_ + row)) * C_ + h * K_ + nt * 16 + ll] = o[nt][r] * inv[r];
    }
  }
}

// ---------------------------------------------------------------------------
// Mixer (unchanged, fp32)
// ---------------------------------------------------------------------------
__global__ __launch_bounds__(256) void mixer_kernel(
    const float* __restrict__ A, const float* __restrict__ Wm,
    const float* __restrict__ bias, float* __restrict__ out) {
  int mt = blockIdx.x, nt = blockIdx.y;
  __shared__ float As[16][65];
  __shared__ float Bs[16][65];
  int tid = threadIdx.x;
  int tx = tid & 15, ty = tid >> 4;
  float acc[4][4] = {};
  int row0 = mt * 64, col0 = nt * 64;

  for (int k0 = 0; k0 < C_; k0 += 16) {
    {
      int m = tid >> 2;
      int kk = (tid & 3) * 4;
      float4 av = *(const float4*)&A[(size_t)(row0 + m) * C_ + k0 + kk];
      As[kk + 0][m] = av.x; As[kk + 1][m] = av.y;
      As[kk + 2][m] = av.z; As[kk + 3][m] = av.w;
    }
    {
      int n = tid >> 2;
      int kk = (tid & 3) * 4;
      float4 bv = *(const float4*)&Wm[(size_t)(col0 + n) * C_ + k0 + kk];
      Bs[kk + 0][n] = bv.x; Bs[kk + 1][n] = bv.y;
      Bs[kk + 2][n] = bv.z; Bs[kk + 3][n] = bv.w;
    }
    __syncthreads();
    #pragma unroll
    for (int kk = 0; kk < 16; ++kk) {
      float a[4], b[4];
      #pragma unroll
      for (int i = 0; i < 4; ++i) a[i] = As[kk][ty + 16 * i];
      #pragma unroll
      for (int j = 0; j < 4; ++j) b[j] = Bs[kk][tx + 16 * j];
      #pragma unroll
      for (int i = 0; i < 4; ++i)
        #pragma unroll
        for (int j = 0; j < 4; ++j) acc[i][j] += a[i] * b[j];
    }
    __syncthreads();
  }

  #pragma unroll
  for (int i = 0; i < 4; ++i) {
    int m = row0 + ty + 16 * i;
    #pragma unroll
    for (int j = 0; j < 4; ++j) {
      int n = col0 + tx + 16 * j;
      out[(size_t)m * C_ + n] = acc[i][j] + bias[n];
    }
  }
}

// ---------------------------------------------------------------------------
extern "C" void kernel_launch(void* const* d_in, const int* in_sizes, int n_in,
                              void* d_out, int out_size, void* d_ws, size_t ws_size,
                              hipStream_t stream) {
  const float* seq1  = (const float*)d_in[0];
  const float* seq2  = (const float*)d_in[1];
  const float* gamma = (const float*)d_in[2];
  const float* beta  = (const float*)d_in[3];
  const float* qp    = (const float*)d_in[4];
  const float* kp    = (const float*)d_in[5];
  const float* vp    = (const float*)d_in[6];
  const float* wm    = (const float*)d_in[7];
  const float* mb    = (const float*)d_in[8];
  float* out = (float*)d_out;

  char* ws = (char*)d_ws;
  const size_t NROW = (size_t)B_ * W_;                 // 4096
  const size_t XSZ = NROW * C_ * sizeof(float);        // 16 MB
  const size_t QSZ = NROW * C_ * sizeof(short);        // 8 MB per bf16 buffer
  float* x1 = (float*)(ws);                            // later: attn out [B,W,C]
  float* x2 = (float*)(ws + XSZ);
  short* qb = (short*)(ws + 2 * XSZ);
  short* kb = (short*)(ws + 2 * XSZ + QSZ);
  short* vtb = (short*)(ws + 2 * XSZ + 2 * QSZ);
  float* attn = x1;

  ln_kernel<<<dim3(2 * (unsigned)NROW), dim3(256), 0, stream>>>(
      seq1, seq2, gamma, beta, x1, x2);
  proj_kernel<<<dim3(64, H_, 3), dim3(256), 0, stream>>>(
      x1, x2, qp, kp, vp, qb, kb, vtb);
  attn_mfma_kernel<<<dim3(W_ / 64, B_ * H_), dim3(256), 0, stream>>>(
      qb, kb, vtb, attn);
  mixer_kernel<<<dim3(64, 16), dim3(256), 0, stream>>>(attn, wm, mb, out);
}

// Round 4
// 382.324 us; speedup vs baseline: 8.0374x; 2.2851x over previous
//
#include <hip/hip_runtime.h>
#include <math.h>

#define B_ 2
#define W_ 2048
#define C_ 1024
#define H_ 16
#define K_ 64
#define LN_EPS 1e-5f

typedef __attribute__((ext_vector_type(8))) short short8;   // 8 bf16 (4 VGPRs)
typedef __attribute__((ext_vector_type(4))) float float4v;  // MFMA C/D frag

__device__ inline unsigned short f2bf(float f) {  // RNE float->bf16
  unsigned u = __float_as_uint(f);
  u += 0x7fffu + ((u >> 16) & 1u);
  return (unsigned short)(u >> 16);
}

__device__ __forceinline__ void gload_lds16(const short* g, short* l) {
  __builtin_amdgcn_global_load_lds(
      (const __attribute__((address_space(1))) void*)g,
      (__attribute__((address_space(3))) void*)l, 16, 0, 0);
}

// ---------------------------------------------------------------------------
// Block-wide sum over 256 threads (4 waves of 64)
// ---------------------------------------------------------------------------
__device__ inline float block_sum(float val) {
  __shared__ float sb[4];
  #pragma unroll
  for (int o = 32; o > 0; o >>= 1) val += __shfl_down(val, o, 64);
  int lane = threadIdx.x & 63, wid = threadIdx.x >> 6;
  if (lane == 0) sb[wid] = val;
  __syncthreads();
  float r = sb[0] + sb[1] + sb[2] + sb[3];
  __syncthreads();
  return r;
}

// ---------------------------------------------------------------------------
// LayerNorm -> bf16 output. One block per row; handles both seq1 and seq2.
// ---------------------------------------------------------------------------
__global__ __launch_bounds__(256) void ln_kernel(
    const float* __restrict__ seq1, const float* __restrict__ seq2,
    const float* __restrict__ gamma, const float* __restrict__ beta,
    short* __restrict__ x1b, short* __restrict__ x2b) {
  int row = blockIdx.x;
  const int nrows = B_ * W_;
  bool first = row < nrows;
  const float* src = first ? seq1 : seq2;
  short* dst = first ? x1b : x2b;
  int r = first ? row : row - nrows;

  const float4* p = (const float4*)(src + (size_t)r * C_);
  float4 v = p[threadIdx.x];
  float mean = block_sum(v.x + v.y + v.z + v.w) * (1.0f / C_);
  float dx = v.x - mean, dy = v.y - mean, dz = v.z - mean, dw = v.w - mean;
  float var = block_sum(dx * dx + dy * dy + dz * dz + dw * dw) * (1.0f / C_);
  float rstd = rsqrtf(var + LN_EPS);

  float4 g = ((const float4*)gamma)[threadIdx.x];
  float4 b = ((const float4*)beta)[threadIdx.x];
  uint2 o;
  o.x = (unsigned)f2bf(dx * rstd * g.x + b.x) |
        ((unsigned)f2bf(dy * rstd * g.y + b.y) << 16);
  o.y = (unsigned)f2bf(dz * rstd * g.z + b.z) |
        ((unsigned)f2bf(dw * rstd * g.w + b.w) << 16);
  ((uint2*)(dst + (size_t)r * C_))[threadIdx.x] = o;
}

// ---------------------------------------------------------------------------
// Weight prep: proj [H,C,K] fp32 -> B^T bf16 [H*K rows][C cols], q scaled by
// 1/sqrt(K) (exact pow2). grid=(C/64, H, 3), block=256, LDS transpose.
// ---------------------------------------------------------------------------
__global__ __launch_bounds__(256) void wprep_proj_kernel(
    const float* __restrict__ qp, const float* __restrict__ kp,
    const float* __restrict__ vp,
    short* __restrict__ wqt, short* __restrict__ wkt, short* __restrict__ wvt) {
  int cb = blockIdx.x, h = blockIdx.y, which = blockIdx.z;
  const float* P = (which == 0 ? qp : (which == 1 ? kp : vp)) + (size_t)h * C_ * K_;
  short* Wt = (which == 0 ? wqt : (which == 1 ? wkt : wvt));
  float scale = (which == 0) ? 0.125f : 1.0f;

  __shared__ float Ls[64][65];
  int t = threadIdx.x;
  {
    int cr = t >> 2, ks = (t & 3) * 16;
    const float* src = P + (size_t)(cb * 64 + cr) * K_ + ks;
    #pragma unroll
    for (int j = 0; j < 4; ++j) {
      float4 v = *(const float4*)(src + j * 4);
      Ls[cr][ks + j * 4 + 0] = v.x; Ls[cr][ks + j * 4 + 1] = v.y;
      Ls[cr][ks + j * 4 + 2] = v.z; Ls[cr][ks + j * 4 + 3] = v.w;
    }
  }
  __syncthreads();
  int kr = t >> 2, cs = (t & 3) * 16;
  unsigned u[8];
  #pragma unroll
  for (int i = 0; i < 8; ++i) {
    float a = Ls[cs + 2 * i][kr] * scale;
    float b = Ls[cs + 2 * i + 1][kr] * scale;
    u[i] = (unsigned)f2bf(a) | ((unsigned)f2bf(b) << 16);
  }
  short* dst = Wt + ((size_t)h * 64 + kr) * C_ + cb * 64 + cs;
  uint4 p0; p0.x = u[0]; p0.y = u[1]; p0.z = u[2]; p0.w = u[3];
  uint4 p1; p1.x = u[4]; p1.y = u[5]; p1.z = u[6]; p1.w = u[7];
  *(uint4*)dst = p0;
  *(uint4*)(dst + 8) = p1;
}

// Mixer weight: plain fp32 -> bf16 (already in B^T form: out@W.T uses W[n][c]).
__global__ __launch_bounds__(256) void wprep_mix_kernel(
    const float* __restrict__ wm, short* __restrict__ wmb) {
  int gid = blockIdx.x * 256 + threadIdx.x;
  float4 v = ((const float4*)wm)[gid];
  uint2 o;
  o.x = (unsigned)f2bf(v.x) | ((unsigned)f2bf(v.y) << 16);
  o.y = (unsigned)f2bf(v.z) | ((unsigned)f2bf(v.w) << 16);
  ((uint2*)wmb)[gid] = o;
}

// ---------------------------------------------------------------------------
// bf16 MFMA GEMM core: C[128x128] tile of A[*,1024] x Bt[*,1024]^T.
// 256 threads = 4 waves (2x2), 16x16x32 MFMA, 4x4 frags/wave, BK=64.
// global_load_lds width-16 staging; XOR-swizzled LDS (conflict-free frags).
// ---------------------------------------------------------------------------
__device__ __forceinline__ void gemm_core(
    const short* __restrict__ A, const short* __restrict__ Bt,
    int arow0, int brow0, short* As, short* Bs, float4v acc[4][4]) {
  int tid = threadIdx.x;
  int wave = tid >> 6, lane = tid & 63;
  int lr = lane >> 3, lc = lane & 7;
  int sc = lc ^ lr;                       // swizzled global chunk for staging
  int wr = wave >> 1, wc = wave & 1;
  int lg = lane >> 4, ll = lane & 15;

  #pragma unroll
  for (int mi = 0; mi < 4; ++mi)
    #pragma unroll
    for (int ni = 0; ni < 4; ++ni) {
      acc[mi][ni][0] = 0.f; acc[mi][ni][1] = 0.f;
      acc[mi][ni][2] = 0.f; acc[mi][ni][3] = 0.f;
    }

  for (int k0 = 0; k0 < C_; k0 += 64) {
    __syncthreads();
    #pragma unroll
    for (int j = 0; j < 4; ++j) {
      int seg = wave * 4 + j;            // 8-row segment of the 128-row tile
      int r = seg * 8 + lr;
      gload_lds16(A + (size_t)(arow0 + r) * C_ + k0 + sc * 8, As + seg * 512);
      gload_lds16(Bt + (size_t)(brow0 + r) * C_ + k0 + sc * 8, Bs + seg * 512);
    }
    __syncthreads();
    #pragma unroll
    for (int kc = 0; kc < 2; ++kc) {
      int cc = kc * 4 + lg;
      short8 af[4], bf[4];
      #pragma unroll
      for (int mi = 0; mi < 4; ++mi) {
        int m = wr * 64 + mi * 16 + ll;
        af[mi] = *(const short8*)&As[m * 64 + ((cc ^ (m & 7)) << 3)];
      }
      #pragma unroll
      for (int ni = 0; ni < 4; ++ni) {
        int n = wc * 64 + ni * 16 + ll;
        bf[ni] = *(const short8*)&Bs[n * 64 + ((cc ^ (n & 7)) << 3)];
      }
      #pragma unroll
      for (int mi = 0; mi < 4; ++mi)
        #pragma unroll
        for (int ni = 0; ni < 4; ++ni)
          acc[mi][ni] = __builtin_amdgcn_mfma_f32_16x16x32_bf16(
              af[mi], bf[ni], acc[mi][ni], 0, 0, 0);
    }
  }
}

// ---------------------------------------------------------------------------
// QKV GEMMs, fused in grid.z: z=0 Q=x1@Wq^T, z=1 K=x2@Wk^T,
// z=2 V^T = Wv x2^T (operand-swapped so stores into [B,H,K,W] coalesce).
// Outputs bf16. grid=(32,8,3).
// ---------------------------------------------------------------------------
__global__ __launch_bounds__(256, 3) void gemm_qkv_kernel(
    const short* __restrict__ x1b, const short* __restrict__ x2b,
    const short* __restrict__ wqt, const short* __restrict__ wkt,
    const short* __restrict__ wvt,
    short* __restrict__ qb, short* __restrict__ kb, short* __restrict__ vtb) {
  __shared__ short As[128 * 64], Bs[128 * 64];
  int z = blockIdx.z;
  const short *A, *Bt;
  int arow0, brow0;
  if (z == 0)      { A = x1b; Bt = wqt; arow0 = blockIdx.x * 128; brow0 = blockIdx.y * 128; }
  else if (z == 1) { A = x2b; Bt = wkt; arow0 = blockIdx.x * 128; brow0 = blockIdx.y * 128; }
  else             { A = wvt; Bt = x2b; arow0 = blockIdx.y * 128; brow0 = blockIdx.x * 128; }

  float4v acc[4][4];
  gemm_core(A, Bt, arow0, brow0, As, Bs, acc);

  int wave = threadIdx.x >> 6, lane = threadIdx.x & 63;
  int wr = wave >> 1, wc = wave & 1, lg = lane >> 4, ll = lane & 15;
  if (z <= 1) {
    short* O = (z == 0) ? qb : kb;
    #pragma unroll
    for (int mi = 0; mi < 4; ++mi)
      #pragma unroll
      for (int ni = 0; ni < 4; ++ni) {
        int n = brow0 + wc * 64 + ni * 16 + ll;       // h*64+k
        int h = n >> 6, kk = n & 63;
        #pragma unroll
        for (int r2 = 0; r2 < 4; ++r2) {
          int m = arow0 + wr * 64 + mi * 16 + lg * 4 + r2;  // seq index
          int b = m >> 11, w = m & (W_ - 1);
          O[((size_t)(b * H_ + h) * W_ + w) * K_ + kk] = (short)f2bf(acc[mi][ni][r2]);
        }
      }
  } else {
    #pragma unroll
    for (int mi = 0; mi < 4; ++mi)
      #pragma unroll
      for (int ni = 0; ni < 4; ++ni) {
        int n = brow0 + wc * 64 + ni * 16 + ll;       // seq index
        int b = n >> 11, w = n & (W_ - 1);
        #pragma unroll
        for (int r2 = 0; r2 < 4; ++r2) {
          int m = arow0 + wr * 64 + mi * 16 + lg * 4 + r2;  // h*64+k
          int h = m >> 6, kk = m & 63;
          vtb[((size_t)(b * H_ + h) * K_ + kk) * W_ + w] = (short)f2bf(acc[mi][ni][r2]);
        }
      }
  }
}

// ---------------------------------------------------------------------------
// Mixer GEMM: out[4096,1024] fp32 = attnb @ wmb^T + bias. grid=(32,8).
// ---------------------------------------------------------------------------
__global__ __launch_bounds__(256, 3) void gemm_mix_kernel(
    const short* __restrict__ attnb, const short* __restrict__ wmb,
    const float* __restrict__ bias, float* __restrict__ out) {
  __shared__ short As[128 * 64], Bs[128 * 64];
  int arow0 = blockIdx.x * 128, brow0 = blockIdx.y * 128;
  float4v acc[4][4];
  gemm_core(attnb, wmb, arow0, brow0, As, Bs, acc);

  int wave = threadIdx.x >> 6, lane = threadIdx.x & 63;
  int wr = wave >> 1, wc = wave & 1, lg = lane >> 4, ll = lane & 15;
  #pragma unroll
  for (int mi = 0; mi < 4; ++mi)
    #pragma unroll
    for (int ni = 0; ni < 4; ++ni) {
      int n = brow0 + wc * 64 + ni * 16 + ll;
      float bv = bias[n];
      #pragma unroll
      for (int r2 = 0; r2 < 4; ++r2) {
        int m = arow0 + wr * 64 + mi * 16 + lg * 4 + r2;
        out[(size_t)m * C_ + n] = acc[mi][ni][r2] + bv;
      }
    }
}

// ---------------------------------------------------------------------------
// Causal flash attention, bf16 MFMA (unchanged from R3 except bf16 output).
// ---------------------------------------------------------------------------
__global__ __launch_bounds__(256) void attn_mfma_kernel(
    const short* __restrict__ q, const short* __restrict__ k,
    const short* __restrict__ vt, short* __restrict__ out) {
  int bh = blockIdx.y;
  int b = bh >> 4, h = bh & 15;
  int qt = (int)gridDim.x - 1 - (int)blockIdx.x;  // heavy tiles first
  int wave = threadIdx.x >> 6;
  int lane = threadIdx.x & 63;
  int lg = lane >> 4;
  int ll = lane & 15;

  const short* qp = q + (size_t)bh * W_ * K_;
  const short* kp = k + (size_t)bh * W_ * K_;
  const short* vb = vt + (size_t)bh * K_ * W_;

  int qrow = qt * 64 + wave * 16 + ll;
  short8 aq[2];
  #pragma unroll
  for (int kc = 0; kc < 2; ++kc)
    aq[kc] = *(const short8*)(qp + (size_t)qrow * K_ + kc * 32 + lg * 8);

  float4v o[4];
  #pragma unroll
  for (int nt = 0; nt < 4; ++nt) { o[nt][0] = 0.f; o[nt][1] = 0.f; o[nt][2] = 0.f; o[nt][3] = 0.f; }
  float m4[4] = {-INFINITY, -INFINITY, -INFINITY, -INFINITY};
  float l4[4] = {};

  __shared__ short Plds[4 * 16 * 72];
  short* myP = &Plds[wave * 16 * 72];

  for (int kt = 0; kt <= qt; ++kt) {
    const short* kbase = kp + (size_t)kt * 64 * K_;
    float4v S[4];
    #pragma unroll
    for (int nt = 0; nt < 4; ++nt) {
      S[nt][0] = 0.f; S[nt][1] = 0.f; S[nt][2] = 0.f; S[nt][3] = 0.f;
      #pragma unroll
      for (int kc = 0; kc < 2; ++kc) {
        short8 bk = *(const short8*)(kbase + (size_t)(nt * 16 + ll) * K_ + kc * 32 + lg * 8);
        S[nt] = __builtin_amdgcn_mfma_f32_16x16x32_bf16(aq[kc], bk, S[nt], 0, 0, 0);
      }
    }
    float sv[4][4];
    #pragma unroll
    for (int nt = 0; nt < 4; ++nt)
      #pragma unroll
      for (int r = 0; r < 4; ++r) sv[nt][r] = S[nt][r];
    if (kt == qt) {
      #pragma unroll
      for (int nt = 0; nt < 4; ++nt) {
        #pragma unroll
        for (int r = 0; r < 4; ++r) {
          int col = nt * 16 + ll;
          int row = wave * 16 + lg * 4 + r;
          if (col > row) sv[nt][r] = -INFINITY;
        }
      }
    }
    float pv[4][4];
    #pragma unroll
    for (int r = 0; r < 4; ++r) {
      float x = fmaxf(fmaxf(sv[0][r], sv[1][r]), fmaxf(sv[2][r], sv[3][r]));
      x = fmaxf(x, __shfl_xor(x, 1, 64));
      x = fmaxf(x, __shfl_xor(x, 2, 64));
      x = fmaxf(x, __shfl_xor(x, 4, 64));
      x = fmaxf(x, __shfl_xor(x, 8, 64));
      float nm = fmaxf(m4[r], x);
      float al = __expf(m4[r] - nm);
      m4[r] = nm;
      float ps = 0.f;
      #pragma unroll
      for (int nt = 0; nt < 4; ++nt) {
        float p = __expf(sv[nt][r] - nm);
        pv[nt][r] = p;
        ps += p;
      }
      ps += __shfl_xor(ps, 1, 64);
      ps += __shfl_xor(ps, 2, 64);
      ps += __shfl_xor(ps, 4, 64);
      ps += __shfl_xor(ps, 8, 64);
      l4[r] = l4[r] * al + ps;
      #pragma unroll
      for (int nt = 0; nt < 4; ++nt) o[nt][r] *= al;
    }
    #pragma unroll
    for (int nt = 0; nt < 4; ++nt)
      #pragma unroll
      for (int r = 0; r < 4; ++r)
        myP[(lg * 4 + r) * 72 + nt * 16 + ll] = (short)f2bf(pv[nt][r]);
    __builtin_amdgcn_s_waitcnt(0xC07F);  // lgkmcnt(0)
    short8 ap[2];
    ap[0] = *(const short8*)(myP + ll * 72 + lg * 8);
    ap[1] = *(const short8*)(myP + ll * 72 + 32 + lg * 8);
    #pragma unroll
    for (int nt = 0; nt < 4; ++nt) {
      #pragma unroll
      for (int kc = 0; kc < 2; ++kc) {
        short8 bv = *(const short8*)(vb + (size_t)(nt * 16 + ll) * W_ + kt * 64 + kc * 32 + lg * 8);
        o[nt] = __builtin_amdgcn_mfma_f32_16x16x32_bf16(ap[kc], bv, o[nt], 0, 0, 0);
      }
    }
  }

  float inv[4];
  #pragma unroll
  for (int r = 0; r < 4; ++r) inv[r] = 1.0f / l4[r];
  #pragma unroll
  for (int nt = 0; nt < 4; ++nt) {
    #pragma unroll
    for (int r = 0; r < 4; ++r) {
      int row = qt * 64 + wave * 16 + lg * 4 + r;
      out[((size_t)(b * W_ + row)) * C_ + h * K_ + nt * 16 + ll] =
          (short)f2bf(o[nt][r] * inv[r]);
    }
  }
}

// ---------------------------------------------------------------------------
extern "C" void kernel_launch(void* const* d_in, const int* in_sizes, int n_in,
                              void* d_out, int out_size, void* d_ws, size_t ws_size,
                              hipStream_t stream) {
  const float* seq1  = (const float*)d_in[0];
  const float* seq2  = (const float*)d_in[1];
  const float* gamma = (const float*)d_in[2];
  const float* beta  = (const float*)d_in[3];
  const float* qp    = (const float*)d_in[4];
  const float* kp    = (const float*)d_in[5];
  const float* vp    = (const float*)d_in[6];
  const float* wm    = (const float*)d_in[7];
  const float* mb    = (const float*)d_in[8];
  float* out = (float*)d_out;

  char* ws = (char*)d_ws;
  const size_t NROW = (size_t)B_ * W_;               // 4096
  const size_t XB = NROW * C_ * sizeof(short);       // 8 MB bf16 activation buf
  const size_t WB = (size_t)C_ * C_ * sizeof(short); // 2 MB bf16 weight buf
  short* x1b = (short*)(ws);
  short* x2b = (short*)(ws + XB);
  short* qb  = (short*)(ws + 2 * XB);
  short* kb  = (short*)(ws + 3 * XB);
  short* vtb = (short*)(ws + 4 * XB);
  short* wqt = (short*)(ws + 5 * XB);
  short* wkt = (short*)(ws + 5 * XB + WB);
  short* wvt = (short*)(ws + 5 * XB + 2 * WB);
  short* wmb = (short*)(ws + 5 * XB + 3 * WB);
  short* attnb = (short*)(ws + 5 * XB + 4 * WB);

  wprep_proj_kernel<<<dim3(C_ / 64, H_, 3), dim3(256), 0, stream>>>(
      qp, kp, vp, wqt, wkt, wvt);
  wprep_mix_kernel<<<dim3(C_ * C_ / 1024), dim3(256), 0, stream>>>(wm, wmb);
  ln_kernel<<<dim3(2 * (unsigned)NROW), dim3(256), 0, stream>>>(
      seq1, seq2, gamma, beta, x1b, x2b);
  gemm_qkv_kernel<<<dim3(32, 8, 3), dim3(256), 0, stream>>>(
      x1b, x2b, wqt, wkt, wvt, qb, kb, vtb);
  attn_mfma_kernel<<<dim3(W_ / 64, B_ * H_), dim3(256), 0, stream>>>(
      qb, kb, vtb, attnb);
  gemm_mix_kernel<<<dim3(32, 8), dim3(256), 0, stream>>>(attnb, wmb, mb, out);
}